// Round 1
// baseline (203.291 us; speedup 1.0000x reference)
//
#include <hip/hip_runtime.h>
#include <hip/hip_bf16.h>

// Problem constants
#define DM   256
#define NH   8
#define HC   32
#define SEQ  512
#define BATCH 2
#define MTOT (BATCH*SEQ)   // 1024 rows

// workspace float offsets
#define OFF_Q   0
#define OFF_K   262144      // (b,h,s,c)
#define OFF_VT  524288      // (b,h,c,s)
#define OFF_X1  786432      // (b,t,d)  x + attn
#define OFF_H   1048576     // (b,t,4d) gelu(fc)
// total 2097152 floats = 8 MB

__device__ __forceinline__ float qgelu(float x) {
    return x / (1.0f + __expf(-1.702f * x));
}

// ---------------------------------------------------------------------------
// Generic 64x64 tiled fp32 GEMM, 256 threads, 4x4 per thread, K-step 16.
// MODE 0: QKV epilogue (bias + scatter q/k/vT into ws)
// MODE 1: FC  epilogue (bias + quick_gelu -> O)
// MODE 2: PROJ epilogue (bias + residual X1 -> O)
// ---------------------------------------------------------------------------
template<int MODE>
__global__ __launch_bounds__(256)
void gemm_k(const float* __restrict__ A, const float* __restrict__ B,
            const float* __restrict__ bias, const float* __restrict__ X1res,
            float* __restrict__ O, float* __restrict__ ws,
            int M, int N, int K)
{
    __shared__ float As[16][68];   // [k][m], padded
    __shared__ float Bs[16][64];   // [k][n]

    const int tid = threadIdx.x;
    const int tx = tid & 15, ty = tid >> 4;
    const int n0 = blockIdx.x * 64, m0 = blockIdx.y * 64;

    const int ar = tid >> 2;            // 0..63 : A tile row
    const int ak = (tid & 3) << 2;      // 0,4,8,12 : A tile k
    const int bk = tid >> 4;            // 0..15 : B tile k
    const int bc = (tid & 15) << 2;     // 0..60 : B tile col

    float acc[4][4] = {};

    for (int k0 = 0; k0 < K; k0 += 16) {
        float4 av = *(const float4*)&A[(size_t)(m0 + ar)*K + k0 + ak];
        float4 bv = *(const float4*)&B[(size_t)(k0 + bk)*N + n0 + bc];
        __syncthreads();
        As[ak+0][ar] = av.x; As[ak+1][ar] = av.y;
        As[ak+2][ar] = av.z; As[ak+3][ar] = av.w;
        *(float4*)&Bs[bk][bc] = bv;
        __syncthreads();
        #pragma unroll
        for (int kk = 0; kk < 16; ++kk) {
            float4 a4 = *(const float4*)&As[kk][ty<<2];
            float4 b4 = *(const float4*)&Bs[kk][tx<<2];
            float a[4] = {a4.x,a4.y,a4.z,a4.w};
            float b[4] = {b4.x,b4.y,b4.z,b4.w};
            #pragma unroll
            for (int i=0;i<4;++i)
                #pragma unroll
                for (int j=0;j<4;++j)
                    acc[i][j] = fmaf(a[i], b[j], acc[i][j]);
        }
    }

    #pragma unroll
    for (int i=0;i<4;++i) {
        const int m = m0 + (ty<<2) + i;
        #pragma unroll
        for (int j=0;j<4;++j) {
            const int n = n0 + (tx<<2) + j;
            float v = acc[i][j] + bias[n];
            if (MODE == 0) {
                const int b = m >> 9, t = m & 511;
                const int h = n / 96, jj = n % 96;
                const int bh = b*NH + h;
                if (jj < 32)      ws[OFF_Q  + ((size_t)(bh*SEQ + t))*HC + jj]        = v;
                else if (jj < 64) ws[OFF_K  + ((size_t)(bh*SEQ + t))*HC + (jj-32)]   = v;
                else              ws[OFF_VT + ((size_t)(bh*HC + (jj-64)))*SEQ + t]   = v;
            } else if (MODE == 1) {
                O[(size_t)m*N + n] = qgelu(v);
            } else {
                O[(size_t)m*N + n] = X1res[(size_t)m*N + n] + v;
            }
        }
    }
}

// ---------------------------------------------------------------------------
// L1-distance attention + residual.
// One block per (b,h, 32-query tile): grid = 2*8*16 = 256 blocks, 256 threads.
// LDS: K rows [512][36] (float4-aligned, conflict-free), V^T [32][516],
//      per-wave softmax row [4][512].  Total 147,968 B (dynamic).
// Each wave processes 8 queries; per query: lanes split s (8 each),
// q row cached in 32 VGPRs, shuffle-reduce softmax, float4 PV.
// ---------------------------------------------------------------------------
#define ATTN_LDS_FLOATS (512*36 + 32*516 + 4*512)

__global__ __launch_bounds__(256)
void attn_k(const float* __restrict__ wq, const float* __restrict__ wk,
            const float* __restrict__ wvt, const float* __restrict__ xin,
            float* __restrict__ x1)
{
    extern __shared__ float lds[];
    float* ks   = lds;               // [512][36]
    float* vt   = lds + 512*36;      // [32][516]
    float* wrow = vt  + 32*516;      // [4][512]

    const int tid  = threadIdx.x;
    const int lane = tid & 63;
    const int wv   = tid >> 6;
    const int gid  = blockIdx.x;
    const int bh   = gid >> 4;
    const int qbase = (gid & 15) * 32;
    const float scale = 0.17677669529663687f;   // 1/sqrt(32)

    const float* kg = wk  + (size_t)bh * (SEQ*HC);
    const float* vg = wvt + (size_t)bh * (HC*SEQ);

    // stage K (b,h,s,c) -> ks[s][36]
    for (int i = tid*4; i < SEQ*HC; i += 1024) {
        const int s = i >> 5, c = i & 31;
        *(float4*)&ks[s*36 + c] = *(const float4*)&kg[i];
    }
    // stage V^T (b,h,c,s) -> vt[c][516]
    for (int i = tid*4; i < HC*SEQ; i += 1024) {
        const int c = i >> 9, s = i & 511;
        *(float4*)&vt[c*516 + s] = *(const float4*)&vg[i];
    }
    __syncthreads();

    const int b = bh >> 3, hh = bh & 7;

    for (int qi = 0; qi < 8; ++qi) {
        const int tl = wv*8 + qi;
        const int t  = qbase + tl;
        const float* qrow = wq + ((size_t)(bh*SEQ + t))*HC;
        float qv[32];
        #pragma unroll
        for (int c4=0;c4<8;++c4) {
            float4 q4 = *(const float4*)&qrow[c4*4];
            qv[c4*4+0]=q4.x; qv[c4*4+1]=q4.y; qv[c4*4+2]=q4.z; qv[c4*4+3]=q4.w;
        }

        // L1 distance -> weight, 8 s-values per lane
        float w[8];
        #pragma unroll
        for (int j=0;j<8;++j) {
            const int s = j*64 + lane;
            const float* krow = &ks[s*36];
            float d = 0.f;
            #pragma unroll
            for (int c4=0;c4<8;++c4) {
                float4 kv = *(const float4*)&krow[c4*4];
                d += fabsf(qv[c4*4+0]-kv.x) + fabsf(qv[c4*4+1]-kv.y)
                   + fabsf(qv[c4*4+2]-kv.z) + fabsf(qv[c4*4+3]-kv.w);
            }
            w[j] = (s == t) ? 0.0f : 1.0f/(0.001f + d*scale);
        }

        // softmax over 512 (8 per lane x 64 lanes)
        float mx = w[0];
        #pragma unroll
        for (int j=1;j<8;++j) mx = fmaxf(mx, w[j]);
        #pragma unroll
        for (int off=32; off>=1; off>>=1) mx = fmaxf(mx, __shfl_xor(mx, off, 64));
        float se = 0.f;
        #pragma unroll
        for (int j=0;j<8;++j) { w[j] = __expf(w[j]-mx); se += w[j]; }
        #pragma unroll
        for (int off=32; off>=1; off>>=1) se += __shfl_xor(se, off, 64);
        const float inv = 1.0f/se;

        #pragma unroll
        for (int j=0;j<8;++j) wrow[wv*512 + j*64 + lane] = w[j];

        // PV: lanes = (half g, channel c); 256 s per half, float4
        const int g = lane >> 5, c = lane & 31;
        const float* vr = &vt[c*516 + g*256];
        const float* wr = &wrow[wv*512 + g*256];
        float acc = 0.f;
        #pragma unroll 8
        for (int s4=0; s4<256; s4+=4) {
            float4 w4 = *(const float4*)&wr[s4];
            float4 v4 = *(const float4*)&vr[s4];
            acc += w4.x*v4.x + w4.y*v4.y + w4.z*v4.z + w4.w*v4.w;
        }
        acc += __shfl_xor(acc, 32, 64);

        if (lane < 32) {
            const int idx = ((b*SEQ + t)*DM) + hh*HC + c;
            x1[idx] = xin[idx] + acc * inv;
        }
    }
}

// ---------------------------------------------------------------------------
extern "C" void kernel_launch(void* const* d_in, const int* in_sizes, int n_in,
                              void* d_out, int out_size, void* d_ws, size_t ws_size,
                              hipStream_t stream)
{
    (void)in_sizes; (void)n_in; (void)out_size; (void)ws_size;
    const float* x     = (const float*)d_in[0];
    const float* Wqkv  = (const float*)d_in[1];
    const float* bqkv  = (const float*)d_in[2];
    const float* Wfc   = (const float*)d_in[3];
    const float* bfc   = (const float*)d_in[4];
    const float* Wproj = (const float*)d_in[5];
    const float* bproj = (const float*)d_in[6];
    float* out = (float*)d_out;
    float* ws  = (float*)d_ws;

    // K1: qkv = x @ W_qkv + b, scatter to q/k/vT
    gemm_k<0><<<dim3(768/64, MTOT/64), 256, 0, stream>>>(
        x, Wqkv, bqkv, nullptr, nullptr, ws, MTOT, 768, DM);

    // K2: attention + residual -> x1
    const int attn_lds = ATTN_LDS_FLOATS * 4;
    hipFuncSetAttribute((const void*)attn_k,
                        hipFuncAttributeMaxDynamicSharedMemorySize, attn_lds);
    attn_k<<<dim3(256), 256, attn_lds, stream>>>(
        ws+OFF_Q, ws+OFF_K, ws+OFF_VT, x, ws+OFF_X1);

    // K3: h = quick_gelu(x1 @ W_fc + b)
    gemm_k<1><<<dim3(1024/64, MTOT/64), 256, 0, stream>>>(
        ws+OFF_X1, Wfc, bfc, nullptr, ws+OFF_H, ws, MTOT, 1024, DM);

    // K4: out = x1 + h @ W_proj + b
    gemm_k<2><<<dim3(256/64, MTOT/64), 256, 0, stream>>>(
        ws+OFF_H, Wproj, bproj, ws+OFF_X1, out, ws, MTOT, 256, 1024);
}

// Round 2
// 155.873 us; speedup vs baseline: 1.3042x; 1.3042x over previous
//
#include <hip/hip_runtime.h>
#include <hip/hip_bf16.h>

// Problem constants
#define DM   256
#define NH   8
#define HC   32
#define SEQ  512
#define BATCH 2
#define MTOT (BATCH*SEQ)   // 1024 rows

// ---------- workspace layout ----------
// fp32 region (float offsets)
#define OFF_Q   0           // (b,h,s,c)  262144
#define OFF_K   262144      // (b,h,s,c)  262144
#define OFF_VT  524288      // (b,h,c,s)  262144
#define OFF_X1  786432      // (b,t,d)    262144
#define FP32_END 1048576    // 4 MB
// bf16 region (element offsets within wsb = (__bf16*)(ws + FP32_END))
#define BOFF_XB     0          // x bf16        [1024][256]
#define BOFF_X1B    262144     // x1 bf16       [1024][256]
#define BOFF_HB     524288     // h bf16        [1024][1024]
#define BOFF_WQKVT  1572864    // Wqkv^T bf16   [768][256]
#define BOFF_WFCT   1769472    // Wfc^T bf16    [1024][256]
#define BOFF_WPROJT 2031616    // Wproj^T bf16  [256][1024]
// bf16 end: 2293760 elems -> total ws = 4 MB + 4.59 MB = 8.6 MB

typedef __attribute__((ext_vector_type(8))) __bf16 bf16x8;
typedef __attribute__((ext_vector_type(4))) __bf16 bf16x4;
typedef __attribute__((ext_vector_type(4))) float  f32x4;

__device__ __forceinline__ float qgelu(float x) {
    return x / (1.0f + __expf(-1.702f * x));
}

// ---------------------------------------------------------------------------
// K0: convert x -> bf16 (straight) and the 3 weights -> bf16 TRANSPOSED [n][k]
// blockIdx.y selects the tensor. Reads are strided (transpose) but fully
// L2/L3-cached; total ~1M elems.
// ---------------------------------------------------------------------------
__device__ __forceinline__ void conv_copy(const float* __restrict__ in,
                                          __bf16* __restrict__ out,
                                          int total, int gid) {
    int o = gid * 4;
    if (o >= total) return;
    float4 v = *(const float4*)(in + o);
    bf16x4 b;
    b.x = (__bf16)v.x; b.y = (__bf16)v.y; b.z = (__bf16)v.z; b.w = (__bf16)v.w;
    *(bf16x4*)(out + o) = b;
}

__device__ __forceinline__ void conv_transpose(const float* __restrict__ in,
                                               __bf16* __restrict__ out,
                                               int K, int N, int gid) {
    int o = gid * 4;                 // output index, k fastest
    if (o >= K * N) return;
    int n = o / K;                   // o%4==0 and K%4==0 -> same n for all 4
    int k = o - n * K;
    bf16x4 b;
    b.x = (__bf16)in[(size_t)(k + 0) * N + n];
    b.y = (__bf16)in[(size_t)(k + 1) * N + n];
    b.z = (__bf16)in[(size_t)(k + 2) * N + n];
    b.w = (__bf16)in[(size_t)(k + 3) * N + n];
    *(bf16x4*)(out + o) = b;
}

__global__ __launch_bounds__(256)
void convert_k(const float* __restrict__ x,
               const float* __restrict__ Wqkv,
               const float* __restrict__ Wfc,
               const float* __restrict__ Wproj,
               __bf16* __restrict__ wsb)
{
    const int gid = blockIdx.x * 256 + threadIdx.x;
    switch (blockIdx.y) {
        case 0: conv_copy(x, wsb + BOFF_XB, MTOT * DM, gid); break;
        case 1: conv_transpose(Wqkv,  wsb + BOFF_WQKVT,  256, 768,  gid); break;
        case 2: conv_transpose(Wfc,   wsb + BOFF_WFCT,   256, 1024, gid); break;
        case 3: conv_transpose(Wproj, wsb + BOFF_WPROJT, 1024, 256, gid); break;
    }
}

// ---------------------------------------------------------------------------
// LDS-free MFMA bf16 GEMM.  A: [M][K_] bf16, Bt: [N][K_] bf16 (pre-transposed).
// Block = 4 waves; wave w computes rows [by*64 + w*16, +16) x cols [bx*64, +64)
// as 4 accum frags of mfma_f32_16x16x32_bf16. No LDS, no barriers: fragment
// loads go straight from global (L2-resident), 8 K-steps unrolled for MLP.
//   A-frag: lane(q=l>>4, r=l&15) reads A[m0+r][kt + q*8 .. +8]  (16B)
//   B-frag: same pattern on Bt rows (n0+nt*16+r)
//   C-frag: col = lane&15, row = q*4 + i  [m89/m91 verified mapping]
// MODE 0: +bias, scatter q/k/vT fp32 into ws
// MODE 1: +bias, quick_gelu -> Ob (bf16)
// MODE 2: +bias, +X1res -> Of (fp32)
// ---------------------------------------------------------------------------
template<int MODE, int K_>
__global__ __launch_bounds__(256)
void mfma_gemm(const __bf16* __restrict__ A, const __bf16* __restrict__ Bt,
               const float* __restrict__ bias, const float* __restrict__ X1res,
               float* __restrict__ Of, __bf16* __restrict__ Ob,
               float* __restrict__ ws, int N)
{
    const int lane = threadIdx.x & 63;
    const int wv   = threadIdx.x >> 6;
    const int m0   = blockIdx.y * 64 + wv * 16;
    const int n0   = blockIdx.x * 64;
    const int r    = lane & 15;
    const int q    = lane >> 4;

    const __bf16* ap = A  + (size_t)(m0 + r) * K_ + q * 8;
    const __bf16* bp = Bt + (size_t)(n0 + r) * K_ + q * 8;

    f32x4 acc[4] = {f32x4{0,0,0,0}, f32x4{0,0,0,0}, f32x4{0,0,0,0}, f32x4{0,0,0,0}};

    #pragma unroll 8
    for (int kt = 0; kt < K_; kt += 32) {
        bf16x8 af = *(const bf16x8*)(ap + kt);
        #pragma unroll
        for (int nt = 0; nt < 4; ++nt) {
            bf16x8 bf = *(const bf16x8*)(bp + (size_t)nt * 16 * K_ + kt);
            acc[nt] = __builtin_amdgcn_mfma_f32_16x16x32_bf16(af, bf, acc[nt], 0, 0, 0);
        }
    }

    #pragma unroll
    for (int nt = 0; nt < 4; ++nt) {
        const int n = n0 + nt * 16 + r;         // C col = lane&15
        const float bn = bias[n];
        #pragma unroll
        for (int i = 0; i < 4; ++i) {
            const int m = m0 + q * 4 + i;       // C row = q*4 + i
            float v = acc[nt][i] + bn;
            if (MODE == 0) {
                const int b  = m >> 9, t = m & 511;
                const int h  = n / 96, jj = n % 96;
                const int bh = b * NH + h;
                if (jj < 32)      ws[OFF_Q  + ((size_t)(bh * SEQ + t)) * HC + jj]       = v;
                else if (jj < 64) ws[OFF_K  + ((size_t)(bh * SEQ + t)) * HC + (jj - 32)] = v;
                else              ws[OFF_VT + ((size_t)(bh * HC + (jj - 64))) * SEQ + t] = v;
            } else if (MODE == 1) {
                Ob[(size_t)m * N + n] = (__bf16)qgelu(v);
            } else {
                Of[(size_t)m * N + n] = X1res[(size_t)m * N + n] + v;
            }
        }
    }
}

// ---------------------------------------------------------------------------
// L1-distance attention + residual (unchanged from round 1 except it also
// emits x1 in bf16 for the FC GEMM's A operand).
// ---------------------------------------------------------------------------
#define ATTN_LDS_FLOATS (512*36 + 32*516 + 4*512)

__global__ __launch_bounds__(256)
void attn_k(const float* __restrict__ wq, const float* __restrict__ wk,
            const float* __restrict__ wvt, const float* __restrict__ xin,
            float* __restrict__ x1, __bf16* __restrict__ x1b)
{
    extern __shared__ float lds[];
    float* ks   = lds;               // [512][36]
    float* vt   = lds + 512*36;      // [32][516]
    float* wrow = vt  + 32*516;      // [4][512]

    const int tid  = threadIdx.x;
    const int lane = tid & 63;
    const int wv   = tid >> 6;
    const int gid  = blockIdx.x;
    const int bh   = gid >> 4;
    const int qbase = (gid & 15) * 32;
    const float scale = 0.17677669529663687f;   // 1/sqrt(32)

    const float* kg = wk  + (size_t)bh * (SEQ*HC);
    const float* vg = wvt + (size_t)bh * (HC*SEQ);

    for (int i = tid*4; i < SEQ*HC; i += 1024) {
        const int s = i >> 5, c = i & 31;
        *(float4*)&ks[s*36 + c] = *(const float4*)&kg[i];
    }
    for (int i = tid*4; i < HC*SEQ; i += 1024) {
        const int c = i >> 9, s = i & 511;
        *(float4*)&vt[c*516 + s] = *(const float4*)&vg[i];
    }
    __syncthreads();

    const int b = bh >> 3, hh = bh & 7;

    for (int qi = 0; qi < 8; ++qi) {
        const int tl = wv*8 + qi;
        const int t  = qbase + tl;
        const float* qrow = wq + ((size_t)(bh*SEQ + t))*HC;
        float qv[32];
        #pragma unroll
        for (int c4=0;c4<8;++c4) {
            float4 q4 = *(const float4*)&qrow[c4*4];
            qv[c4*4+0]=q4.x; qv[c4*4+1]=q4.y; qv[c4*4+2]=q4.z; qv[c4*4+3]=q4.w;
        }

        float w[8];
        #pragma unroll
        for (int j=0;j<8;++j) {
            const int s = j*64 + lane;
            const float* krow = &ks[s*36];
            float d = 0.f;
            #pragma unroll
            for (int c4=0;c4<8;++c4) {
                float4 kv = *(const float4*)&krow[c4*4];
                d += fabsf(qv[c4*4+0]-kv.x) + fabsf(qv[c4*4+1]-kv.y)
                   + fabsf(qv[c4*4+2]-kv.z) + fabsf(qv[c4*4+3]-kv.w);
            }
            w[j] = (s == t) ? 0.0f : 1.0f/(0.001f + d*scale);
        }

        float mx = w[0];
        #pragma unroll
        for (int j=1;j<8;++j) mx = fmaxf(mx, w[j]);
        #pragma unroll
        for (int off=32; off>=1; off>>=1) mx = fmaxf(mx, __shfl_xor(mx, off, 64));
        float se = 0.f;
        #pragma unroll
        for (int j=0;j<8;++j) { w[j] = __expf(w[j]-mx); se += w[j]; }
        #pragma unroll
        for (int off=32; off>=1; off>>=1) se += __shfl_xor(se, off, 64);
        const float inv = 1.0f/se;

        #pragma unroll
        for (int j=0;j<8;++j) wrow[wv*512 + j*64 + lane] = w[j];

        const int g = lane >> 5, c = lane & 31;
        const float* vr = &vt[c*516 + g*256];
        const float* wr = &wrow[wv*512 + g*256];
        float acc = 0.f;
        #pragma unroll 8
        for (int s4=0; s4<256; s4+=4) {
            float4 w4 = *(const float4*)&wr[s4];
            float4 v4 = *(const float4*)&vr[s4];
            acc += w4.x*v4.x + w4.y*v4.y + w4.z*v4.z + w4.w*v4.w;
        }
        acc += __shfl_xor(acc, 32, 64);

        if (lane < 32) {
            const int idx = ((b*SEQ + t)*DM) + hh*HC + c;
            const float r = xin[idx] + acc * inv;
            x1[idx]  = r;
            x1b[idx] = (__bf16)r;
        }
    }
}

// ---------------------------------------------------------------------------
extern "C" void kernel_launch(void* const* d_in, const int* in_sizes, int n_in,
                              void* d_out, int out_size, void* d_ws, size_t ws_size,
                              hipStream_t stream)
{
    (void)in_sizes; (void)n_in; (void)out_size; (void)ws_size;
    const float* x     = (const float*)d_in[0];
    const float* Wqkv  = (const float*)d_in[1];
    const float* bqkv  = (const float*)d_in[2];
    const float* Wfc   = (const float*)d_in[3];
    const float* bfc   = (const float*)d_in[4];
    const float* Wproj = (const float*)d_in[5];
    const float* bproj = (const float*)d_in[6];
    float* out = (float*)d_out;
    float* ws  = (float*)d_ws;
    __bf16* wsb = (__bf16*)(ws + FP32_END);

    // K0: bf16 conversions + weight transposes
    convert_k<<<dim3(256, 4), 256, 0, stream>>>(x, Wqkv, Wfc, Wproj, wsb);

    // K1: qkv = x @ W_qkv + b  (MFMA), scatter q/k/vT fp32
    mfma_gemm<0, 256><<<dim3(768/64, MTOT/64), 256, 0, stream>>>(
        wsb + BOFF_XB, wsb + BOFF_WQKVT, bqkv, nullptr, nullptr, nullptr, ws, 768);

    // K2: attention + residual -> x1 (fp32 + bf16)
    const int attn_lds = ATTN_LDS_FLOATS * 4;
    hipFuncSetAttribute((const void*)attn_k,
                        hipFuncAttributeMaxDynamicSharedMemorySize, attn_lds);
    attn_k<<<dim3(256), 256, attn_lds, stream>>>(
        ws+OFF_Q, ws+OFF_K, ws+OFF_VT, x, ws+OFF_X1, wsb + BOFF_X1B);

    // K3: h = quick_gelu(x1 @ W_fc + b) -> bf16
    mfma_gemm<1, 256><<<dim3(1024/64, MTOT/64), 256, 0, stream>>>(
        wsb + BOFF_X1B, wsb + BOFF_WFCT, bfc, nullptr, nullptr, wsb + BOFF_HB, ws, 1024);

    // K4: out = x1 + h @ W_proj + b
    mfma_gemm<2, 1024><<<dim3(256/64, MTOT/64), 256, 0, stream>>>(
        wsb + BOFF_HB, wsb + BOFF_WPROJT, bproj, ws+OFF_X1, out, nullptr, ws, 256);
}

// Round 3
// 116.770 us; speedup vs baseline: 1.7410x; 1.3349x over previous
//
#include <hip/hip_runtime.h>
#include <hip/hip_bf16.h>

// Problem constants
#define DM   256
#define NH   8
#define HC   32
#define SEQ  512
#define BATCH 2
#define MTOT (BATCH*SEQ)   // 1024 rows

// ---------- workspace layout ----------
// fp32 region (float offsets)
#define OFF_Q    0          // (bh,t,c)  262144
#define OFF_K    262144     // (bh,s,c)  262144
#define OFF_X1   524288     // (b,t,d)   262144
#define FP32_END 786432     // 3 MB
// bf16 region (element offsets within wsb)
#define BOFF_XB     0          // x bf16        [1024][256]
#define BOFF_X1B    262144     // x1 bf16       [1024][256]
#define BOFF_HB     524288     // h bf16        [1024][1024]
#define BOFF_VTB    1572864    // V^T bf16      [16][32][512]
#define BOFF_WQKVT  1835008    // Wqkv^T bf16   [768][256]
#define BOFF_WFCT   2031616    // Wfc^T bf16    [1024][256]
#define BOFF_WPROJT 2293760    // Wproj^T bf16  [256][1024]
// end 2556004 elems -> ws total = 3 MB + 5.12 MB = 8.1 MB

typedef __attribute__((ext_vector_type(8))) __bf16 bf16x8;
typedef __attribute__((ext_vector_type(4))) __bf16 bf16x4;
typedef __attribute__((ext_vector_type(4))) float  f32x4;

__device__ __forceinline__ float qgelu(float x) {
    return x / (1.0f + __expf(-1.702f * x));
}

// ---------------------------------------------------------------------------
// K0: x -> bf16; weights -> bf16 transposed [n][k]
// ---------------------------------------------------------------------------
__device__ __forceinline__ void conv_copy(const float* __restrict__ in,
                                          __bf16* __restrict__ out,
                                          int total, int gid) {
    int o = gid * 4;
    if (o >= total) return;
    float4 v = *(const float4*)(in + o);
    bf16x4 b;
    b.x = (__bf16)v.x; b.y = (__bf16)v.y; b.z = (__bf16)v.z; b.w = (__bf16)v.w;
    *(bf16x4*)(out + o) = b;
}

__device__ __forceinline__ void conv_transpose(const float* __restrict__ in,
                                               __bf16* __restrict__ out,
                                               int K, int N, int gid) {
    int o = gid * 4;
    if (o >= K * N) return;
    int n = o / K;
    int k = o - n * K;
    bf16x4 b;
    b.x = (__bf16)in[(size_t)(k + 0) * N + n];
    b.y = (__bf16)in[(size_t)(k + 1) * N + n];
    b.z = (__bf16)in[(size_t)(k + 2) * N + n];
    b.w = (__bf16)in[(size_t)(k + 3) * N + n];
    *(bf16x4*)(out + o) = b;
}

__global__ __launch_bounds__(256)
void convert_k(const float* __restrict__ x,
               const float* __restrict__ Wqkv,
               const float* __restrict__ Wfc,
               const float* __restrict__ Wproj,
               __bf16* __restrict__ wsb)
{
    const int gid = blockIdx.x * 256 + threadIdx.x;
    switch (blockIdx.y) {
        case 0: conv_copy(x, wsb + BOFF_XB, MTOT * DM, gid); break;
        case 1: conv_transpose(Wqkv,  wsb + BOFF_WQKVT,  256, 768,  gid); break;
        case 2: conv_transpose(Wfc,   wsb + BOFF_WFCT,   256, 1024, gid); break;
        case 3: conv_transpose(Wproj, wsb + BOFF_WPROJT, 1024, 256, gid); break;
    }
}

// ---------------------------------------------------------------------------
// LDS-free MFMA bf16 GEMM, ONE 16x16 tile per wave (high wave count to hide
// L2-hit latency). A:[M][K_] bf16, Bt:[N][K_] bf16.
// grid = (N/64, M/16), 256 thr = 4 waves, wave wv -> n-tile bx*64+wv*16.
// MODE 0: +bias, scatter q/k fp32 + V^T bf16      (QKV)
// MODE 1: +bias, quick_gelu -> Ob bf16            (FC)
// MODE 2: +bias, +X1res -> Of fp32                (PROJ)
// ---------------------------------------------------------------------------
template<int MODE, int K_>
__global__ __launch_bounds__(256)
void mfma_gemm(const __bf16* __restrict__ A, const __bf16* __restrict__ Bt,
               const float* __restrict__ bias, const float* __restrict__ X1res,
               float* __restrict__ Of, __bf16* __restrict__ Ob,
               float* __restrict__ ws, __bf16* __restrict__ vtb, int N)
{
    const int lane = threadIdx.x & 63;
    const int wv   = threadIdx.x >> 6;
    const int m0   = blockIdx.y * 16;
    const int n0   = blockIdx.x * 64 + wv * 16;
    const int r    = lane & 15;
    const int q    = lane >> 4;

    const __bf16* ap = A  + (size_t)(m0 + r) * K_ + q * 8;
    const __bf16* bp = Bt + (size_t)(n0 + r) * K_ + q * 8;

    f32x4 acc = {0.f, 0.f, 0.f, 0.f};
    #pragma unroll
    for (int kt = 0; kt < K_; kt += 32) {
        bf16x8 af = *(const bf16x8*)(ap + kt);
        bf16x8 bf = *(const bf16x8*)(bp + kt);
        acc = __builtin_amdgcn_mfma_f32_16x16x32_bf16(af, bf, acc, 0, 0, 0);
    }

    const int n = n0 + r;                 // C col = lane&15
    const float bn = bias[n];
    #pragma unroll
    for (int i = 0; i < 4; ++i) {
        const int m = m0 + q * 4 + i;     // C row = q*4 + i
        float v = acc[i] + bn;
        if (MODE == 0) {
            const int b  = m >> 9, t = m & 511;
            const int h  = n / 96, jj = n % 96;
            const int bh = b * NH + h;
            if (jj < 32)      ws[OFF_Q + ((size_t)(bh * SEQ + t)) * HC + jj]        = v;
            else if (jj < 64) ws[OFF_K + ((size_t)(bh * SEQ + t)) * HC + (jj - 32)] = v;
            else              vtb[((size_t)(bh * HC + (jj - 64))) * SEQ + t] = (__bf16)v;
        } else if (MODE == 1) {
            Ob[(size_t)m * N + n] = (__bf16)qgelu(v);
        } else {
            Of[(size_t)m * N + n] = X1res[(size_t)m * N + n] + v;
        }
    }
}

// ---------------------------------------------------------------------------
// L1-distance attention + residual, K-in-registers version.
// Block = 512 threads (8 waves); thread tid <-> s index; K row in 32 VGPRs.
// Grid = 16 bh x 32 q-tiles (16 queries) = 512 blocks.
// Phase 1: per query, q broadcast from LDS, distance fully in registers,
//          exp WITHOUT max-subtraction (weights bounded ~1.5), butterfly sum,
//          p -> LDS bf16 [16][514].
// Phase 2: waves 0,1 do PV via MFMA (A = p from LDS, B = V^T bf16 global),
//          scale by 1/sum, + residual -> x1 fp32 + bf16.
// ---------------------------------------------------------------------------
#define QT 16
#define PSTRIDE 514   // bank = (r + 4q) % 32 on A-frag reads: <=4-way

__global__ __launch_bounds__(512, 4)
void attn_k(const float* __restrict__ wq, const float* __restrict__ wk,
            const __bf16* __restrict__ vtb, const float* __restrict__ xin,
            float* __restrict__ x1, __bf16* __restrict__ x1b)
{
    __shared__ float  qtile[QT * 32];
    __shared__ __bf16 pmat[QT * PSTRIDE];
    __shared__ float  psum[QT * 8];
    __shared__ float  pinv[QT];

    const int tid  = threadIdx.x;
    const int lane = tid & 63;
    const int wv   = tid >> 6;
    const int sg   = tid;                       // s index, 0..511
    const int bh   = blockIdx.x >> 5;
    const int qbase = (blockIdx.x & 31) * QT;
    const float scale = 0.17677669529663687f;   // 1/sqrt(32)

    // stage this thread's K row into registers
    const float* krow = wk + ((size_t)(bh * SEQ + sg)) * HC;
    float kr[32];
    #pragma unroll
    for (int j = 0; j < 8; ++j) {
        float4 k4 = *(const float4*)&krow[j * 4];
        kr[j*4+0] = k4.x; kr[j*4+1] = k4.y; kr[j*4+2] = k4.z; kr[j*4+3] = k4.w;
    }
    // stage q tile (16 x 32 fp32)
    if (tid < QT * 32 / 4) {
        *(float4*)&qtile[tid * 4] =
            *(const float4*)&wq[((size_t)(bh * SEQ + qbase)) * HC + tid * 4];
    }
    __syncthreads();

    #pragma unroll 4
    for (int t = 0; t < QT; ++t) {
        float d = 0.f;
        #pragma unroll
        for (int j = 0; j < 8; ++j) {
            float4 q4 = *(const float4*)&qtile[t * 32 + j * 4];   // broadcast
            d += fabsf(kr[j*4+0] - q4.x) + fabsf(kr[j*4+1] - q4.y)
               + fabsf(kr[j*4+2] - q4.z) + fabsf(kr[j*4+3] - q4.w);
        }
        float w = 1.0f / (0.001f + d * scale);
        if (sg == qbase + t) w = 0.0f;          // diag: weight=0 (still in softmax)
        float p = __expf(w);                    // w in (0,~1.5]: no max needed
        float se = p;
        #pragma unroll
        for (int off = 32; off >= 1; off >>= 1) se += __shfl_xor(se, off, 64);
        pmat[t * PSTRIDE + sg] = (__bf16)p;
        if (lane == 0) psum[t * 8 + wv] = se;
    }
    __syncthreads();

    if (tid < QT) {
        float s = 0.f;
        #pragma unroll
        for (int j = 0; j < 8; ++j) s += psum[tid * 8 + j];
        pinv[tid] = 1.0f / s;
    }
    __syncthreads();

    // PV: waves 0,1; wave wv covers channels [wv*16, wv*16+16)
    if (wv < 2) {
        const int r = lane & 15, q = lane >> 4;
        const __bf16* bp  = vtb + ((size_t)(bh * HC + wv * 16 + r)) * SEQ + q * 8;
        const __bf16* apm = &pmat[r * PSTRIDE + q * 8];

        f32x4 acc = {0.f, 0.f, 0.f, 0.f};
        #pragma unroll
        for (int kt = 0; kt < SEQ; kt += 32) {
            bf16x8 af = *(const bf16x8*)(apm + kt);
            bf16x8 bf = *(const bf16x8*)(bp + kt);
            acc = __builtin_amdgcn_mfma_f32_16x16x32_bf16(af, bf, acc, 0, 0, 0);
        }

        const int b = bh >> 3, hh = bh & 7;
        const int c = wv * 16 + r;
        #pragma unroll
        for (int i = 0; i < 4; ++i) {
            const int tl = q * 4 + i;
            const int t  = qbase + tl;
            const float v = acc[i] * pinv[tl];
            const int idx = ((b * SEQ + t) * DM) + hh * HC + c;
            const float res = xin[idx] + v;
            x1[idx]  = res;
            x1b[idx] = (__bf16)res;
        }
    }
}

// ---------------------------------------------------------------------------
extern "C" void kernel_launch(void* const* d_in, const int* in_sizes, int n_in,
                              void* d_out, int out_size, void* d_ws, size_t ws_size,
                              hipStream_t stream)
{
    (void)in_sizes; (void)n_in; (void)out_size; (void)ws_size;
    const float* x     = (const float*)d_in[0];
    const float* Wqkv  = (const float*)d_in[1];
    const float* bqkv  = (const float*)d_in[2];
    const float* Wfc   = (const float*)d_in[3];
    const float* bfc   = (const float*)d_in[4];
    const float* Wproj = (const float*)d_in[5];
    const float* bproj = (const float*)d_in[6];
    float* out = (float*)d_out;
    float* ws  = (float*)d_ws;
    __bf16* wsb = (__bf16*)(ws + FP32_END);

    // K0: bf16 conversions + weight transposes
    convert_k<<<dim3(256, 4), 256, 0, stream>>>(x, Wqkv, Wfc, Wproj, wsb);

    // K1: qkv = x @ W_qkv + b, scatter q/k fp32 + V^T bf16
    mfma_gemm<0, 256><<<dim3(768/64, MTOT/16), 256, 0, stream>>>(
        wsb + BOFF_XB, wsb + BOFF_WQKVT, bqkv, nullptr,
        nullptr, nullptr, ws, wsb + BOFF_VTB, 768);

    // K2: attention + residual -> x1 (fp32 + bf16)
    attn_k<<<dim3(512), 512, 0, stream>>>(
        ws + OFF_Q, ws + OFF_K, wsb + BOFF_VTB, x, ws + OFF_X1, wsb + BOFF_X1B);

    // K3: h = quick_gelu(x1 @ W_fc + b) -> bf16
    mfma_gemm<1, 256><<<dim3(1024/64, MTOT/16), 256, 0, stream>>>(
        wsb + BOFF_X1B, wsb + BOFF_WFCT, bfc, nullptr,
        nullptr, wsb + BOFF_HB, ws, nullptr, 1024);

    // K4: out = x1 + h @ W_proj + b
    mfma_gemm<2, 1024><<<dim3(256/64, MTOT/16), 256, 0, stream>>>(
        wsb + BOFF_HB, wsb + BOFF_WPROJT, bproj, ws + OFF_X1,
        out, nullptr, ws, nullptr, 256);
}